// Round 11
// baseline (2857.309 us; speedup 1.0000x reference)
//
#include <hip/hip_runtime.h>
#include <stdint.h>

// Named kernel matching the original stub symbol (harmless; kept for loader).
__global__ void MHA_CVRP_solver_23089744183363_kernel() {}

// ---------------------------------------------------------------------------
// JAX threefry2x32 (20 rounds), exact replication
// ---------------------------------------------------------------------------
__device__ __forceinline__ void threefry2x32(uint32_t k0, uint32_t k1,
                                             uint32_t x0, uint32_t x1,
                                             uint32_t& o0, uint32_t& o1) {
  uint32_t ks2 = k0 ^ k1 ^ 0x1BD11BDAu;
  x0 += k0; x1 += k1;
#define TF_R(r) { x0 += x1; x1 = (x1 << (r)) | (x1 >> (32 - (r))); x1 ^= x0; }
  TF_R(13) TF_R(15) TF_R(26) TF_R(6)
  x0 += k1; x1 += ks2 + 1u;
  TF_R(17) TF_R(29) TF_R(16) TF_R(24)
  x0 += ks2; x1 += k0 + 2u;
  TF_R(13) TF_R(15) TF_R(26) TF_R(6)
  x0 += k0; x1 += k1 + 3u;
  TF_R(17) TF_R(29) TF_R(16) TF_R(24)
  x0 += k1; x1 += ks2 + 4u;
  TF_R(13) TF_R(15) TF_R(26) TF_R(6)
  x0 += ks2; x1 += k0 + 5u;
#undef TF_R
  o0 = x0; o1 = x1;
}

// ---------------------------------------------------------------------------
// k_att: fused QKV + attention per (b,head). grid 4096, block 256.
// ---------------------------------------------------------------------------
__global__ __launch_bounds__(256) void k_att(
    const float* __restrict__ statics, const float* __restrict__ w_static,
    const float* __restrict__ b_static, const float* __restrict__ Wq,
    const float* __restrict__ Wk, const float* __restrict__ Wv,
    float* __restrict__ mh_g) {
  __shared__ __align__(16) float ws2[256];
  __shared__ __align__(16) float bss[128];
  __shared__ __align__(16) float wst[6144];   // [3][128][16]
  __shared__ __align__(16) float qh[2560];    // [128][20]
  __shared__ __align__(16) float kh[2560];
  __shared__ __align__(16) float vh[2560];
  const int tid = threadIdx.x;
  const int b = (int)blockIdx.x >> 3;
  const int head = (int)blockIdx.x & 7;

  ws2[tid] = w_static[tid];
  if (tid < 128) bss[tid] = b_static[tid];
  for (int i = tid; i < 2048; i += 256) {
    int k = i >> 4, d = i & 15;
    int so = k * 128 + head * 16 + d;
    wst[i]        = Wq[so];
    wst[2048 + i] = Wk[so];
    wst[4096 + i] = Wv[so];
  }
  __syncthreads();

  {
    const int s = tid >> 1, d0 = (tid & 1) * 8;
    const float st0 = statics[b * 256 + s];
    const float st1 = statics[b * 256 + 128 + s];
    float aq[8], ak[8], av[8];
#pragma unroll
    for (int i = 0; i < 8; ++i) { aq[i] = 0.f; ak[i] = 0.f; av[i] = 0.f; }
    for (int k = 0; k < 128; ++k) {
      float e0v = fmaf(st1, ws2[2 * k + 1], st0 * ws2[2 * k]) + bss[k];
      const float* wq = wst + k * 16 + d0;
      const float* wk = wst + 2048 + k * 16 + d0;
      const float* wv = wst + 4096 + k * 16 + d0;
#pragma unroll
      for (int l = 0; l < 8; ++l) {
        aq[l] = fmaf(e0v, wq[l], aq[l]);
        ak[l] = fmaf(e0v, wk[l], ak[l]);
        av[l] = fmaf(e0v, wv[l], av[l]);
      }
    }
    float* qd = qh + s * 20 + d0;
    float* kd = kh + s * 20 + d0;
    float* vd = vh + s * 20 + d0;
#pragma unroll
    for (int l = 0; l < 8; ++l) { qd[l] = aq[l]; kd[l] = ak[l]; vd[l] = av[l]; }
  }
  __syncthreads();

  const int rq = tid >> 2;
  const int q4 = tid & 3;
  const int j0 = q4 * 32;
  float qA[16], qB[16];
  {
    const float4* pa = (const float4*)(qh + rq * 20);
    const float4* pb = (const float4*)(qh + (rq + 64) * 20);
#pragma unroll
    for (int l = 0; l < 4; ++l) {
      float4 va = pa[l], vb = pb[l];
      qA[4 * l] = va.x; qA[4 * l + 1] = va.y; qA[4 * l + 2] = va.z; qA[4 * l + 3] = va.w;
      qB[4 * l] = vb.x; qB[4 * l + 1] = vb.y; qB[4 * l + 2] = vb.z; qB[4 * l + 3] = vb.w;
    }
  }
  float sA[32], sB[32];
#pragma unroll
  for (int j = 0; j < 32; ++j) {
    const float4* kp = (const float4*)(kh + (j0 + j) * 20);
    float4 k0 = kp[0], k1 = kp[1], k2 = kp[2], k3 = kp[3];
    float kr[16] = {k0.x, k0.y, k0.z, k0.w, k1.x, k1.y, k1.z, k1.w,
                    k2.x, k2.y, k2.z, k2.w, k3.x, k3.y, k3.z, k3.w};
    float dA = qA[0] * kr[0], dB = qB[0] * kr[0];
#pragma unroll
    for (int l = 1; l < 16; ++l) { dA = fmaf(qA[l], kr[l], dA); dB = fmaf(qB[l], kr[l], dB); }
    sA[j] = 0.25f * dA; sB[j] = 0.25f * dB;
  }
  float mA = sA[0], mB = sB[0];
#pragma unroll
  for (int j = 1; j < 32; ++j) { mA = fmaxf(mA, sA[j]); mB = fmaxf(mB, sB[j]); }
  mA = fmaxf(mA, __shfl_xor(mA, 1, 64)); mA = fmaxf(mA, __shfl_xor(mA, 2, 64));
  mB = fmaxf(mB, __shfl_xor(mB, 1, 64)); mB = fmaxf(mB, __shfl_xor(mB, 2, 64));
  float sumA = 0.f, sumB = 0.f;
#pragma unroll
  for (int j = 0; j < 32; ++j) {
    float eA = expf(sA[j] - mA); sA[j] = eA; sumA += eA;
    float eB = expf(sB[j] - mB); sB[j] = eB; sumB += eB;
  }
  sumA += __shfl_xor(sumA, 1, 64); sumA += __shfl_xor(sumA, 2, 64);
  sumB += __shfl_xor(sumB, 1, 64); sumB += __shfl_xor(sumB, 2, 64);
  const float rA = 1.0f / sumA, rB = 1.0f / sumB;
  float aA[16], aB[16];
#pragma unroll
  for (int l = 0; l < 16; ++l) { aA[l] = 0.f; aB[l] = 0.f; }
#pragma unroll
  for (int j = 0; j < 32; ++j) {
    const float4* vp = (const float4*)(vh + (j0 + j) * 20);
    float4 v0 = vp[0], v1 = vp[1], v2 = vp[2], v3 = vp[3];
    float vr[16] = {v0.x, v0.y, v0.z, v0.w, v1.x, v1.y, v1.z, v1.w,
                    v2.x, v2.y, v2.z, v2.w, v3.x, v3.y, v3.z, v3.w};
    float pA = sA[j] * rA, pB = sB[j] * rB;
#pragma unroll
    for (int l = 0; l < 16; ++l) { aA[l] = fmaf(pA, vr[l], aA[l]); aB[l] = fmaf(pB, vr[l], aB[l]); }
  }
#pragma unroll
  for (int l = 0; l < 16; ++l) {
    aA[l] += __shfl_xor(aA[l], 1, 64); aA[l] += __shfl_xor(aA[l], 2, 64);
    aB[l] += __shfl_xor(aB[l], 1, 64); aB[l] += __shfl_xor(aB[l], 2, 64);
  }
  if (q4 == 0) {
    const size_t base = (size_t)b * 16384 + head * 16;
    float4* dA = (float4*)(mh_g + base + rq * 128);
    dA[0] = make_float4(aA[0], aA[1], aA[2], aA[3]);
    dA[1] = make_float4(aA[4], aA[5], aA[6], aA[7]);
    dA[2] = make_float4(aA[8], aA[9], aA[10], aA[11]);
    dA[3] = make_float4(aA[12], aA[13], aA[14], aA[15]);
    float4* dB = (float4*)(mh_g + base + (rq + 64) * 128);
    dB[0] = make_float4(aB[0], aB[1], aB[2], aB[3]);
    dB[1] = make_float4(aB[4], aB[5], aB[6], aB[7]);
    dB[2] = make_float4(aB[8], aB[9], aB[10], aB[11]);
    dB[3] = make_float4(aB[12], aB[13], aB[14], aB[15]);
  }
}

// ---------------------------------------------------------------------------
// k_out: emb = e0 + mh @ Wo, per b.
// ---------------------------------------------------------------------------
__global__ __launch_bounds__(256) void k_out(
    const float* __restrict__ mh_g, const float* __restrict__ Wo,
    const float* __restrict__ statics, const float* __restrict__ w_static,
    const float* __restrict__ b_static, float* __restrict__ emb_g) {
  __shared__ __align__(16) float As[32 * 132];
  __shared__ __align__(16) float Bs[32 * 132];
  __shared__ __align__(16) float ws2[256];
  __shared__ __align__(16) float bss[128];
  const int tid = threadIdx.x;
  const int b = (int)blockIdx.x;
  ws2[tid] = w_static[tid];
  if (tid < 128) bss[tid] = b_static[tid];
  const int ls = tid >> 1, lk = (tid & 1) * 16;
  const int ty = tid >> 4, tx = tid & 15;
  const int lbk = tid >> 3, ljb = (tid & 7) * 16;
  float acc[8][8];
#pragma unroll
  for (int r = 0; r < 8; ++r)
#pragma unroll
    for (int c = 0; c < 8; ++c) acc[r][c] = 0.f;
  __syncthreads();
  for (int kc = 0; kc < 4; ++kc) {
#pragma unroll
    for (int j4 = 0; j4 < 4; ++j4) {
      float4 v = *(const float4*)(mh_g + (size_t)b * 16384 + ls * 128 + kc * 32 + lk + 4 * j4);
      As[(lk + 4 * j4 + 0) * 132 + ls] = v.x;
      As[(lk + 4 * j4 + 1) * 132 + ls] = v.y;
      As[(lk + 4 * j4 + 2) * 132 + ls] = v.z;
      As[(lk + 4 * j4 + 3) * 132 + ls] = v.w;
    }
    {
      const float* src = Wo + (kc * 32 + lbk) * 128 + ljb;
      float* dst = Bs + lbk * 132 + ljb;
#pragma unroll
      for (int l = 0; l < 16; ++l) dst[l] = src[l];
    }
    __syncthreads();
#pragma unroll 4
    for (int kk = 0; kk < 32; ++kk) {
      float4 a0 = *(const float4*)(As + kk * 132 + ty * 8);
      float4 a1 = *(const float4*)(As + kk * 132 + ty * 8 + 4);
      float4 b0 = *(const float4*)(Bs + kk * 132 + tx * 8);
      float4 b1 = *(const float4*)(Bs + kk * 132 + tx * 8 + 4);
      float avv[8] = {a0.x, a0.y, a0.z, a0.w, a1.x, a1.y, a1.z, a1.w};
      float bvv[8] = {b0.x, b0.y, b0.z, b0.w, b1.x, b1.y, b1.z, b1.w};
#pragma unroll
      for (int r = 0; r < 8; ++r)
#pragma unroll
        for (int c = 0; c < 8; ++c) acc[r][c] = fmaf(avv[r], bvv[c], acc[r][c]);
    }
    __syncthreads();
  }
#pragma unroll
  for (int r = 0; r < 8; ++r) {
    int row = ty * 8 + r;
    float s0 = statics[b * 256 + row];
    float s1 = statics[b * 256 + 128 + row];
    float ov[8];
#pragma unroll
    for (int c = 0; c < 8; ++c) {
      int j = tx * 8 + c;
      float e0 = fmaf(s1, ws2[2 * j + 1], s0 * ws2[2 * j]) + bss[j];
      ov[c] = e0 + acc[r][c];
    }
    float4* dst = (float4*)(emb_g + (size_t)b * 16384 + row * 128 + tx * 8);
    dst[0] = make_float4(ov[0], ov[1], ov[2], ov[3]);
    dst[1] = make_float4(ov[4], ov[5], ov[6], ov[7]);
  }
}

// ---------------------------------------------------------------------------
// k_base: baseC = emb @ W1^T + wd0*dy0 + wd1*dy1, per b.
// ---------------------------------------------------------------------------
__global__ __launch_bounds__(256) void k_base(
    const float* __restrict__ emb_g, const float* __restrict__ W1,
    const float* __restrict__ W2, const float* __restrict__ w_dyn,
    const float* __restrict__ dynamics, float* __restrict__ baseC_g) {
  __shared__ __align__(16) float As[32 * 132];
  __shared__ __align__(16) float Bs[32 * 132];
  __shared__ __align__(16) float wd0[128];
  __shared__ __align__(16) float wd1[128];
  __shared__ __align__(16) float dy0[128];
  __shared__ __align__(16) float dy1[128];
  const int tid = threadIdx.x;
  const int b = (int)blockIdx.x;
  if (tid < 128) {
    float A0 = 0.f, A1 = 0.f;
    const float* w2r = W2 + tid * 128;
    for (int k = 0; k < 128; ++k) {
      float w = w2r[k];
      A0 = fmaf(w, w_dyn[2 * k], A0);
      A1 = fmaf(w, w_dyn[2 * k + 1], A1);
    }
    wd0[tid] = A0; wd1[tid] = A1;
    dy0[tid] = dynamics[b * 256 + tid];
    dy1[tid] = dynamics[b * 256 + 128 + tid];
  }
  const int ls = tid >> 1, lk = (tid & 1) * 16;
  const int ty = tid >> 4, tx = tid & 15;
  float acc[8][8];
#pragma unroll
  for (int r = 0; r < 8; ++r)
#pragma unroll
    for (int c = 0; c < 8; ++c) acc[r][c] = 0.f;
  __syncthreads();
  for (int kc = 0; kc < 4; ++kc) {
#pragma unroll
    for (int j4 = 0; j4 < 4; ++j4) {
      float4 v = *(const float4*)(emb_g + (size_t)b * 16384 + ls * 128 + kc * 32 + lk + 4 * j4);
      As[(lk + 4 * j4 + 0) * 132 + ls] = v.x;
      As[(lk + 4 * j4 + 1) * 132 + ls] = v.y;
      As[(lk + 4 * j4 + 2) * 132 + ls] = v.z;
      As[(lk + 4 * j4 + 3) * 132 + ls] = v.w;
    }
    {
      const float* src = W1 + ls * 128 + kc * 32 + lk;
#pragma unroll
      for (int l = 0; l < 16; ++l) Bs[(lk + l) * 132 + ls] = src[l];
    }
    __syncthreads();
#pragma unroll 4
    for (int kk = 0; kk < 32; ++kk) {
      float4 a0 = *(const float4*)(As + kk * 132 + ty * 8);
      float4 a1 = *(const float4*)(As + kk * 132 + ty * 8 + 4);
      float4 b0 = *(const float4*)(Bs + kk * 132 + tx * 8);
      float4 b1 = *(const float4*)(Bs + kk * 132 + tx * 8 + 4);
      float avv[8] = {a0.x, a0.y, a0.z, a0.w, a1.x, a1.y, a1.z, a1.w};
      float bvv[8] = {b0.x, b0.y, b0.z, b0.w, b1.x, b1.y, b1.z, b1.w};
#pragma unroll
      for (int r = 0; r < 8; ++r)
#pragma unroll
        for (int c = 0; c < 8; ++c) acc[r][c] = fmaf(avv[r], bvv[c], acc[r][c]);
    }
    __syncthreads();
  }
#pragma unroll
  for (int r = 0; r < 8; ++r) {
    int row = ty * 8 + r;
    float d0 = dy0[row], d1 = dy1[row];
    float ov[8];
#pragma unroll
    for (int c = 0; c < 8; ++c) {
      int h = tx * 8 + c;
      ov[c] = fmaf(wd1[h], d1, fmaf(wd0[h], d0, acc[r][c]));
    }
    float4* dst = (float4*)(baseC_g + (size_t)b * 16384 + row * 128 + tx * 8);
    dst[0] = make_float4(ov[0], ov[1], ov[2], ov[3]);
    dst[1] = make_float4(ov[4], ov[5], ov[6], ov[7]);
  }
}

// ---------------------------------------------------------------------------
// k_dec: persistent decoder, TWO batches per WG, 512 threads, grid 256.
// R22 = R21 (best: 1653 us; B-slot gumbel, in-wave C, G-fold, 8 barriers,
// no spill) + ONE delta:
//  - phase D INTERLEAVED: the two batch-independent 32-iteration tanh/FMA
//    chains are interleaved per-j for 2x chain ILP (halves D's exposed
//    tanh-dependency latency). Per-batch accumulation order unchanged
//    (acc sums batch0 terms in the same j order; acc1v likewise) -> 
//    bit-exact. This was part of R14's spilling bundle; applied ALONE on
//    the no-spill R21 base to isolate whether it fits in 128 VGPRs.
// Decision rule (pre-committed): WRITE > 200 MB or no gain -> revert to
// R21 and declare the structural floor.
// ---------------------------------------------------------------------------
__global__ __launch_bounds__(512, 2) void k_dec(
    const float* __restrict__ baseC_g, const float* __restrict__ statics,
    const float* __restrict__ dynamics, const float* __restrict__ W_ih,
    const float* __restrict__ W_hh, const float* __restrict__ b_ih,
    const float* __restrict__ b_hh, const float* __restrict__ w_dec_in,
    const float* __restrict__ W2, const float* __restrict__ w_dyn,
    const float* __restrict__ W3, const float* __restrict__ v_att,
    float* __restrict__ out) {
  __shared__ __align__(16) float bC0s[32 * 512];   // [j][tid], 64 KiB
  __shared__ __align__(16) float bC1s[32 * 512];   // [j][tid], 64 KiB
  __shared__ __align__(16) float hbuf0[128], hbuf1[128];
  __shared__ __align__(16) float cbuf0[128], cbuf1[128];
  __shared__ __align__(16) float hrep0[544], hrep1[544];  // 4 copies, stride 136
  __shared__ __align__(16) float gpre0[512], gpre1[512];
  __shared__ __align__(16) float rep0[528], rep1[528];   // 4 copies, stride 132
  __shared__ __align__(16) float vrep[528];
  __shared__ __align__(16) float scb0[128], scb1[128];
  __shared__ __align__(16) float wd1c[128];
  __shared__ __align__(16) float dyn0s[128], dyn1s[128];
  __shared__ __align__(16) float sst0[256], sst1[256];
  __shared__ float rmax0[2], rmax1[2], rsum0[2], rsum1[2], rval0[2], rval1[2];
  __shared__ int ridx0[2], ridx1[2];
  __shared__ float ssel0[2], ssel1[2];
  __shared__ int ptr0S, ptr1S;

  const int tid = threadIdx.x;
  const int b0 = (int)blockIdx.x * 2;
  const int b1 = b0 + 1;

  // W_hh row -> registers (shared across both batches)
  float wh[128];
  {
    const float4* src = (const float4*)(W_hh + tid * 128);
#pragma unroll
    for (int q = 0; q < 32; ++q) {
      float4 v = src[q];
      wh[4 * q] = v.x; wh[4 * q + 1] = v.y; wh[4 * q + 2] = v.z; wh[4 * q + 3] = v.w;
    }
  }
  // Phase C layout: row u = tid>>2, k-chunk kc = tid&3. W3 slice contiguous:
  // W3[(tid>>2)*128 + (tid&3)*32 + i] == W3[tid*32 + i].
  const int uC = tid >> 2, kcC = tid & 3;
  float w3r[32];
  {
    const float4* src = (const float4*)(W3 + tid * 32);
#pragma unroll
    for (int q = 0; q < 8; ++q) {
      float4 v = src[q];
      w3r[4 * q] = v.x; w3r[4 * q + 1] = v.y; w3r[4 * q + 2] = v.z; w3r[4 * q + 3] = v.w;
    }
  }

  float a0 = 0.f, a1 = 0.f;
  {
    const float* wr = W_ih + tid * 128;
    for (int k = 0; k < 128; ++k) {
      float w = wr[k];
      a0 = fmaf(w, w_dec_in[2 * k], a0);
      a1 = fmaf(w, w_dec_in[2 * k + 1], a1);
    }
  }
  const float bsum = b_ih[tid] + b_hh[tid];

  if (tid < 128) {
    float acc1 = 0.f;
    const float* w2r = W2 + tid * 128;
    for (int k = 0; k < 128; ++k) acc1 = fmaf(w2r[k], w_dyn[2 * k + 1], acc1);
    wd1c[tid] = acc1;
    dyn0s[tid] = dynamics[b0 * 256 + 128 + tid];
    dyn1s[tid] = dynamics[b1 * 256 + 128 + tid];
    hbuf0[tid] = 0.f; cbuf0[tid] = 0.f;
    hbuf1[tid] = 0.f; cbuf1[tid] = 0.f;
    float nv = v_att[tid];
    vrep[tid] = nv; vrep[132 + tid] = nv; vrep[264 + tid] = nv; vrep[396 + tid] = nv;
  }
  if (tid < 256) {
    sst0[tid] = statics[b0 * 256 + tid];
    sst1[tid] = statics[b1 * 256 + tid];
  }
  const int sD = tid >> 2, qD = tid & 3;
  // baseC slices -> LDS (transposed: element j of thread's slice at [j][tid])
  {
    const float4* s0 = (const float4*)(baseC_g + (size_t)b0 * 16384 + sD * 128 + qD * 32);
    const float4* s1 = (const float4*)(baseC_g + (size_t)b1 * 16384 + sD * 128 + qD * 32);
#pragma unroll
    for (int j = 0; j < 8; ++j) {
      float4 v = s0[j];
      bC0s[(4 * j + 0) * 512 + tid] = v.x;
      bC0s[(4 * j + 1) * 512 + tid] = v.y;
      bC0s[(4 * j + 2) * 512 + tid] = v.z;
      bC0s[(4 * j + 3) * 512 + tid] = v.w;
      float4 w = s1[j];
      bC1s[(4 * j + 0) * 512 + tid] = w.x;
      bC1s[(4 * j + 1) * 512 + tid] = w.y;
      bC1s[(4 * j + 2) * 512 + tid] = w.z;
      bC1s[(4 * j + 3) * 512 + tid] = w.w;
    }
  }
  __syncthreads();
  float xa0 = a0 + a1, xa1 = a0 + a1;

  const int laneBase = (tid & 63) & ~3;   // lane of kc==0 thread in this group

  for (int t = 0; t < 128; ++t) {
    float gum = 0.f;   // set in the B-slot by waves 0,1 (b0) and 4,5 (b1)

    // phase A: gate pre-activation for gate-row tid, both batches
    // (sequential per-batch loops, R13-identical codegen)
    {
      float acc0 = bsum + xa0;
      const float4* hp0 = (const float4*)hbuf0;
#pragma unroll
      for (int q = 0; q < 32; ++q) {
        float4 hv = hp0[q];
        acc0 = fmaf(wh[4 * q], hv.x, acc0);
        acc0 = fmaf(wh[4 * q + 1], hv.y, acc0);
        acc0 = fmaf(wh[4 * q + 2], hv.z, acc0);
        acc0 = fmaf(wh[4 * q + 3], hv.w, acc0);
      }
      gpre0[tid] = acc0;
      float acc1v = bsum + xa1;
      const float4* hp1 = (const float4*)hbuf1;
#pragma unroll
      for (int q = 0; q < 32; ++q) {
        float4 hv = hp1[q];
        acc1v = fmaf(wh[4 * q], hv.x, acc1v);
        acc1v = fmaf(wh[4 * q + 1], hv.y, acc1v);
        acc1v = fmaf(wh[4 * q + 2], hv.z, acc1v);
        acc1v = fmaf(wh[4 * q + 3], hv.w, acc1v);
      }
      gpre1[tid] = acc1v;
    }
    __syncthreads();
    // phase B: LSTM remapped to waves 2,3 (b0) and 6,7 (b1) -- per-row math
    // identical to R17, only the executing thread changed. Idle waves
    // 0,1 (tid<128) and 4,5 (tid 256..383) -- exactly E3's executors --
    // compute their own element's gumbel here (fk threefry + element
    // threefry + logs), hiding the serial RNG chain under the LSTM.
    if (tid >= 128 && tid < 256) {
      int u = tid - 128;
      float gi = gpre0[u], gf = gpre0[128 + u], gg = gpre0[256 + u], go = gpre0[384 + u];
      float si = 1.f / (1.f + expf(-gi));
      float sf = 1.f / (1.f + expf(-gf));
      float so = 1.f / (1.f + expf(-go));
      float cn = sf * cbuf0[u] + si * tanhf(gg);
      float hn = so * tanhf(cn);
      cbuf0[u] = cn; hbuf0[u] = hn;
      hrep0[u] = hn; hrep0[136 + u] = hn;
      hrep0[272 + u] = hn; hrep0[408 + u] = hn;
    } else if (tid >= 384) {
      int u = tid - 384;
      float gi = gpre1[u], gf = gpre1[128 + u], gg = gpre1[256 + u], go = gpre1[384 + u];
      float si = 1.f / (1.f + expf(-gi));
      float sf = 1.f / (1.f + expf(-gf));
      float so = 1.f / (1.f + expf(-go));
      float cn = sf * cbuf1[u] + si * tanhf(gg);
      float hn = so * tanhf(cn);
      cbuf1[u] = cn; hbuf1[u] = hn;
      hrep1[u] = hn; hrep1[136 + u] = hn;
      hrep1[272 + u] = hn; hrep1[408 + u] = hn;
    } else {
      // tid < 128: gum for b0 element tid; 256 <= tid < 384: b1, element
      // tid-256. Same fk derivation + element mapping as R17's E3.
      const int lE = (tid < 128) ? tid : (tid - 256);
      const int bb = (tid < 128) ? b0 : b1;
      uint32_t fk0, fk1, o0, o1;
      threefry2x32(0u, 42u, 0u, (uint32_t)t, fk0, fk1);   // fold_in(key(42),t)
      threefry2x32(fk0, fk1, 0u, (uint32_t)(bb * 128 + lE), o0, o1);
      uint32_t bits = o0 ^ o1;
      float f = __uint_as_float(0x3f800000u | (bits >> 9)) - 1.0f;
      float uu = (f > 0.0f) ? f : 1.17549435e-38f;
      gum = logf(-logf(uu));
    }
    __syncthreads();
    // phase C: in-wave (h @ W3^T). Thread (uC, kcC) computes partial kcC of
    // row uC from rotated copy kcC (word base kcC*168): banks
    // {4j, 8+4j, 16+4j, 24+4j} across the 4 lanes -> conflict-free.
    // FMA chain order and 4-partial combine identical to R13's hw3p path.
    {
      const float4* hp0 = (const float4*)(hrep0 + kcC * 168);
      float p0 = 0.f;
#pragma unroll
      for (int j = 0; j < 8; ++j) {
        float4 hv = hp0[j];
        p0 = fmaf(w3r[4 * j], hv.x, p0); p0 = fmaf(w3r[4 * j + 1], hv.y, p0);
        p0 = fmaf(w3r[4 * j + 2], hv.z, p0); p0 = fmaf(w3r[4 * j + 3], hv.w, p0);
      }
      const float4* hp1 = (const float4*)(hrep1 + kcC * 168);
      float p1 = 0.f;
#pragma unroll
      for (int j = 0; j < 8; ++j) {
        float4 hv = hp1[j];
        p1 = fmaf(w3r[4 * j], hv.x, p1); p1 = fmaf(w3r[4 * j + 1], hv.y, p1);
        p1 = fmaf(w3r[4 * j + 2], hv.z, p1); p1 = fmaf(w3r[4 * j + 3], hv.w, p1);
      }
      float g0 = __shfl(p0, laneBase, 64);
      float g1 = __shfl(p0, laneBase + 1, 64);
      float g2 = __shfl(p0, laneBase + 2, 64);
      float g3 = __shfl(p0, laneBase + 3, 64);
      rep0[kcC * 132 + uC] = ((g0 + g1) + g2) + g3;
      float h0v = __shfl(p1, laneBase, 64);
      float h1v = __shfl(p1, laneBase + 1, 64);
      float h2v = __shfl(p1, laneBase + 2, 64);
      float h3v = __shfl(p1, laneBase + 3, 64);
      rep1[kcC * 132 + uC] = ((h0v + h1v) + h2v) + h3v;
    }
    __syncthreads();
    // phase D: score partials, both batches INTERLEAVED per-j for 2x chain
    // ILP (per-batch FMA/tanh order identical to R21: acc sums batch0
    // terms in j order, acc1v sums batch1 terms in j order -> bit-exact).
    // bC reads conflict-free: bank = tid%32.
    {
      const float* vp = vrep + 164 * qD;
      const float* h0 = rep0 + 164 * qD;
      const float* h1 = rep1 + 164 * qD;
      float acc = 0.f, acc1v = 0.f;
#pragma unroll
      for (int j = 0; j < 32; ++j) {
        acc   = fmaf(vp[j], tanhf(bC0s[j * 512 + tid] + h0[j]), acc);
        acc1v = fmaf(vp[j], tanhf(bC1s[j * 512 + tid] + h1[j]), acc1v);
      }
      acc += __shfl_xor(acc, 1, 64);
      acc += __shfl_xor(acc, 2, 64);
      acc1v += __shfl_xor(acc1v, 1, 64);
      acc1v += __shfl_xor(acc1v, 2, 64);
      if (qD == 0) { scb0[sD] = acc; scb1[sD] = acc1v; }
    }
    __syncthreads();
    // phase E: log-softmax + gumbel argmax; group0 = tid<128 (b0),
    // group1 = 256<=tid<384 (b1); R17's exact 2-wave shfl+LDS structure,
    // with the gumbel already in-register from the B-slot.
    const int g0 = (tid < 128);
    const int g1 = (tid >= 256 && tid < 384);
    const int lE = g0 ? tid : (tid - 256);
    float scv = 0.f, lpv = 0.f, mrow = 0.f;
    if (g0 || g1) {
      scv = g0 ? scb0[lE] : scb1[lE];
      float m = scv;
#pragma unroll
      for (int off = 32; off; off >>= 1) m = fmaxf(m, __shfl_xor(m, off, 64));
      if ((lE & 63) == 0) { if (g0) rmax0[lE >> 6] = m; else rmax1[lE >> 6] = m; }
    }
    __syncthreads();
    if (g0 || g1) {
      mrow = g0 ? fmaxf(rmax0[0], rmax0[1]) : fmaxf(rmax1[0], rmax1[1]);
      float sum = expf(scv - mrow);
#pragma unroll
      for (int off = 32; off; off >>= 1) sum += __shfl_xor(sum, off, 64);
      if ((lE & 63) == 0) { if (g0) rsum0[lE >> 6] = sum; else rsum1[lE >> 6] = sum; }
    }
    __syncthreads();
    if (g0 || g1) {
      float sum = g0 ? (rsum0[0] + rsum0[1]) : (rsum1[0] + rsum1[1]);
      lpv = (scv - mrow) - logf(sum);
      float val = lpv - gum;
      int idx = lE;
#pragma unroll
      for (int off = 32; off; off >>= 1) {
        float ov = __shfl_xor(val, off, 64);
        int oi = __shfl_xor(idx, off, 64);
        if (ov > val || (ov == val && oi < idx)) { val = ov; idx = oi; }
      }
      if ((lE & 63) == 0) {
        if (g0) { rval0[lE >> 6] = val; ridx0[lE >> 6] = idx; }
        else    { rval1[lE >> 6] = val; ridx1[lE >> 6] = idx; }
      }
    }
    __syncthreads();
    if (g0 || g1) {
      int p;
      if (g0) { float v0 = rval0[0], v1 = rval0[1];
                p = (v1 > v0) ? ridx0[1] : ridx0[0]; }
      else    { float v0 = rval1[0], v1 = rval1[1];
                p = (v1 > v0) ? ridx1[1] : ridx1[0]; }
      p &= 127;
      int bb = g0 ? b0 : b1;
      if (lE == 0) {
        if (g0) ptr0S = p; else ptr1S = p;
        out[bb * 128 + t] = (float)p;
      }
      if (lE == p) {
        out[65536 + bb * 128 + t] = lpv;
        const float* sst = g0 ? sst0 : sst1;
        float s0v = sst[p], s1v = sst[128 + p];
        if (g0) { ssel0[0] = s0v; ssel0[1] = s1v; }
        else    { ssel1[0] = s0v; ssel1[1] = s1v; }
      }
    }
    __syncthreads();
    // phase G: rank-1 baseC corrections (own-column LDS, single-owner, no
    // cross-thread hazard) + dyn zeroing folded into the reading wave +
    // next decoder inputs. No trailing barrier.
    {
      int p0 = ptr0S, p1 = ptr1S;
      if (sD == p0) {
        float d1 = dyn0s[p0];
#pragma unroll
        for (int i = 0; i < 32; ++i)
          bC0s[i * 512 + tid] = fmaf(-wd1c[qD * 32 + i], d1, bC0s[i * 512 + tid]);
        if (qD == 0) dyn0s[p0] = 0.f;
      }
      if (sD == p1) {
        float d1 = dyn1s[p1];
#pragma unroll
        for (int i = 0; i < 32; ++i)
          bC1s[i * 512 + tid] = fmaf(-wd1c[qD * 32 + i], d1, bC1s[i * 512 + tid]);
        if (qD == 0) dyn1s[p1] = 0.f;
      }
      xa0 = fmaf(a0, ssel0[0], a1 * ssel0[1]);
      xa1 = fmaf(a0, ssel1[0], a1 * ssel1[1]);
    }
  }
}

// ---------------------------------------------------------------------------
extern "C" __attribute__((visibility("default")))
void kernel_launch(void* const* d_in, const int* in_sizes, int n_in,
                   void* d_out, int out_size, void* d_ws, size_t ws_size,
                   hipStream_t stream) {
  (void)hipGetLastError();
  (void)in_sizes; (void)n_in; (void)out_size; (void)ws_size;

  const float* statics  = (const float*)d_in[0];
  const float* dynamics = (const float*)d_in[1];
  // d_in[2] = distances: unused by the reference; never touched.
  const float* w_static = (const float*)d_in[3];
  const float* b_static = (const float*)d_in[4];
  const float* Wq  = (const float*)d_in[5];
  const float* Wk  = (const float*)d_in[6];
  const float* Wv  = (const float*)d_in[7];
  const float* Wo  = (const float*)d_in[8];
  const float* w_dyn    = (const float*)d_in[9];
  const float* w_dec_in = (const float*)d_in[10];
  const float* W_ih = (const float*)d_in[11];
  const float* W_hh = (const float*)d_in[12];
  const float* b_ih = (const float*)d_in[13];
  const float* b_hh = (const float*)d_in[14];
  const float* W1   = (const float*)d_in[15];
  const float* W2   = (const float*)d_in[16];
  const float* W3   = (const float*)d_in[17];
  const float* v_att = (const float*)d_in[18];
  float* wsA = (float*)d_ws;            // emb
  float* wsB = wsA + 8388608;           // mh, then baseC
  float* outp = (float*)d_out;

  k_att<<<dim3(4096), dim3(256), 0, stream>>>(
      statics, w_static, b_static, Wq, Wk, Wv, wsB);
  k_out<<<dim3(512), dim3(256), 0, stream>>>(
      wsB, Wo, statics, w_static, b_static, wsA);
  k_base<<<dim3(512), dim3(256), 0, stream>>>(
      wsA, W1, W2, w_dyn, dynamics, wsB);
  k_dec<<<dim3(256), dim3(512), 0, stream>>>(
      wsB, statics, dynamics, W_ih, W_hh, b_ih, b_hh, w_dec_in,
      W2, w_dyn, W3, v_att, outp);
}

// Round 12
// 1984.114 us; speedup vs baseline: 1.4401x; 1.4401x over previous
//
#include <hip/hip_runtime.h>
#include <stdint.h>

// Named kernel matching the original stub symbol (harmless; kept for loader).
__global__ void MHA_CVRP_solver_23089744183363_kernel() {}

// ---------------------------------------------------------------------------
// JAX threefry2x32 (20 rounds), exact replication
// ---------------------------------------------------------------------------
__device__ __forceinline__ void threefry2x32(uint32_t k0, uint32_t k1,
                                             uint32_t x0, uint32_t x1,
                                             uint32_t& o0, uint32_t& o1) {
  uint32_t ks2 = k0 ^ k1 ^ 0x1BD11BDAu;
  x0 += k0; x1 += k1;
#define TF_R(r) { x0 += x1; x1 = (x1 << (r)) | (x1 >> (32 - (r))); x1 ^= x0; }
  TF_R(13) TF_R(15) TF_R(26) TF_R(6)
  x0 += k1; x1 += ks2 + 1u;
  TF_R(17) TF_R(29) TF_R(16) TF_R(24)
  x0 += ks2; x1 += k0 + 2u;
  TF_R(13) TF_R(15) TF_R(26) TF_R(6)
  x0 += k0; x1 += k1 + 3u;
  TF_R(17) TF_R(29) TF_R(16) TF_R(24)
  x0 += k1; x1 += ks2 + 4u;
  TF_R(13) TF_R(15) TF_R(26) TF_R(6)
  x0 += ks2; x1 += k0 + 5u;
#undef TF_R
  o0 = x0; o1 = x1;
}

// ---------------------------------------------------------------------------
// k_att: fused QKV + attention per (b,head). grid 4096, block 256.
// ---------------------------------------------------------------------------
__global__ __launch_bounds__(256) void k_att(
    const float* __restrict__ statics, const float* __restrict__ w_static,
    const float* __restrict__ b_static, const float* __restrict__ Wq,
    const float* __restrict__ Wk, const float* __restrict__ Wv,
    float* __restrict__ mh_g) {
  __shared__ __align__(16) float ws2[256];
  __shared__ __align__(16) float bss[128];
  __shared__ __align__(16) float wst[6144];   // [3][128][16]
  __shared__ __align__(16) float qh[2560];    // [128][20]
  __shared__ __align__(16) float kh[2560];
  __shared__ __align__(16) float vh[2560];
  const int tid = threadIdx.x;
  const int b = (int)blockIdx.x >> 3;
  const int head = (int)blockIdx.x & 7;

  ws2[tid] = w_static[tid];
  if (tid < 128) bss[tid] = b_static[tid];
  for (int i = tid; i < 2048; i += 256) {
    int k = i >> 4, d = i & 15;
    int so = k * 128 + head * 16 + d;
    wst[i]        = Wq[so];
    wst[2048 + i] = Wk[so];
    wst[4096 + i] = Wv[so];
  }
  __syncthreads();

  {
    const int s = tid >> 1, d0 = (tid & 1) * 8;
    const float st0 = statics[b * 256 + s];
    const float st1 = statics[b * 256 + 128 + s];
    float aq[8], ak[8], av[8];
#pragma unroll
    for (int i = 0; i < 8; ++i) { aq[i] = 0.f; ak[i] = 0.f; av[i] = 0.f; }
    for (int k = 0; k < 128; ++k) {
      float e0v = fmaf(st1, ws2[2 * k + 1], st0 * ws2[2 * k]) + bss[k];
      const float* wq = wst + k * 16 + d0;
      const float* wk = wst + 2048 + k * 16 + d0;
      const float* wv = wst + 4096 + k * 16 + d0;
#pragma unroll
      for (int l = 0; l < 8; ++l) {
        aq[l] = fmaf(e0v, wq[l], aq[l]);
        ak[l] = fmaf(e0v, wk[l], ak[l]);
        av[l] = fmaf(e0v, wv[l], av[l]);
      }
    }
    float* qd = qh + s * 20 + d0;
    float* kd = kh + s * 20 + d0;
    float* vd = vh + s * 20 + d0;
#pragma unroll
    for (int l = 0; l < 8; ++l) { qd[l] = aq[l]; kd[l] = ak[l]; vd[l] = av[l]; }
  }
  __syncthreads();

  const int rq = tid >> 2;
  const int q4 = tid & 3;
  const int j0 = q4 * 32;
  float qA[16], qB[16];
  {
    const float4* pa = (const float4*)(qh + rq * 20);
    const float4* pb = (const float4*)(qh + (rq + 64) * 20);
#pragma unroll
    for (int l = 0; l < 4; ++l) {
      float4 va = pa[l], vb = pb[l];
      qA[4 * l] = va.x; qA[4 * l + 1] = va.y; qA[4 * l + 2] = va.z; qA[4 * l + 3] = va.w;
      qB[4 * l] = vb.x; qB[4 * l + 1] = vb.y; qB[4 * l + 2] = vb.z; qB[4 * l + 3] = vb.w;
    }
  }
  float sA[32], sB[32];
#pragma unroll
  for (int j = 0; j < 32; ++j) {
    const float4* kp = (const float4*)(kh + (j0 + j) * 20);
    float4 k0 = kp[0], k1 = kp[1], k2 = kp[2], k3 = kp[3];
    float kr[16] = {k0.x, k0.y, k0.z, k0.w, k1.x, k1.y, k1.z, k1.w,
                    k2.x, k2.y, k2.z, k2.w, k3.x, k3.y, k3.z, k3.w};
    float dA = qA[0] * kr[0], dB = qB[0] * kr[0];
#pragma unroll
    for (int l = 1; l < 16; ++l) { dA = fmaf(qA[l], kr[l], dA); dB = fmaf(qB[l], kr[l], dB); }
    sA[j] = 0.25f * dA; sB[j] = 0.25f * dB;
  }
  float mA = sA[0], mB = sB[0];
#pragma unroll
  for (int j = 1; j < 32; ++j) { mA = fmaxf(mA, sA[j]); mB = fmaxf(mB, sB[j]); }
  mA = fmaxf(mA, __shfl_xor(mA, 1, 64)); mA = fmaxf(mA, __shfl_xor(mA, 2, 64));
  mB = fmaxf(mB, __shfl_xor(mB, 1, 64)); mB = fmaxf(mB, __shfl_xor(mB, 2, 64));
  float sumA = 0.f, sumB = 0.f;
#pragma unroll
  for (int j = 0; j < 32; ++j) {
    float eA = expf(sA[j] - mA); sA[j] = eA; sumA += eA;
    float eB = expf(sB[j] - mB); sB[j] = eB; sumB += eB;
  }
  sumA += __shfl_xor(sumA, 1, 64); sumA += __shfl_xor(sumA, 2, 64);
  sumB += __shfl_xor(sumB, 1, 64); sumB += __shfl_xor(sumB, 2, 64);
  const float rA = 1.0f / sumA, rB = 1.0f / sumB;
  float aA[16], aB[16];
#pragma unroll
  for (int l = 0; l < 16; ++l) { aA[l] = 0.f; aB[l] = 0.f; }
#pragma unroll
  for (int j = 0; j < 32; ++j) {
    const float4* vp = (const float4*)(vh + (j0 + j) * 20);
    float4 v0 = vp[0], v1 = vp[1], v2 = vp[2], v3 = vp[3];
    float vr[16] = {v0.x, v0.y, v0.z, v0.w, v1.x, v1.y, v1.z, v1.w,
                    v2.x, v2.y, v2.z, v2.w, v3.x, v3.y, v3.z, v3.w};
    float pA = sA[j] * rA, pB = sB[j] * rB;
#pragma unroll
    for (int l = 0; l < 16; ++l) { aA[l] = fmaf(pA, vr[l], aA[l]); aB[l] = fmaf(pB, vr[l], aB[l]); }
  }
#pragma unroll
  for (int l = 0; l < 16; ++l) {
    aA[l] += __shfl_xor(aA[l], 1, 64); aA[l] += __shfl_xor(aA[l], 2, 64);
    aB[l] += __shfl_xor(aB[l], 1, 64); aB[l] += __shfl_xor(aB[l], 2, 64);
  }
  if (q4 == 0) {
    const size_t base = (size_t)b * 16384 + head * 16;
    float4* dA = (float4*)(mh_g + base + rq * 128);
    dA[0] = make_float4(aA[0], aA[1], aA[2], aA[3]);
    dA[1] = make_float4(aA[4], aA[5], aA[6], aA[7]);
    dA[2] = make_float4(aA[8], aA[9], aA[10], aA[11]);
    dA[3] = make_float4(aA[12], aA[13], aA[14], aA[15]);
    float4* dB = (float4*)(mh_g + base + (rq + 64) * 128);
    dB[0] = make_float4(aB[0], aB[1], aB[2], aB[3]);
    dB[1] = make_float4(aB[4], aB[5], aB[6], aB[7]);
    dB[2] = make_float4(aB[8], aB[9], aB[10], aB[11]);
    dB[3] = make_float4(aB[12], aB[13], aB[14], aB[15]);
  }
}

// ---------------------------------------------------------------------------
// k_out: emb = e0 + mh @ Wo, per b.
// ---------------------------------------------------------------------------
__global__ __launch_bounds__(256) void k_out(
    const float* __restrict__ mh_g, const float* __restrict__ Wo,
    const float* __restrict__ statics, const float* __restrict__ w_static,
    const float* __restrict__ b_static, float* __restrict__ emb_g) {
  __shared__ __align__(16) float As[32 * 132];
  __shared__ __align__(16) float Bs[32 * 132];
  __shared__ __align__(16) float ws2[256];
  __shared__ __align__(16) float bss[128];
  const int tid = threadIdx.x;
  const int b = (int)blockIdx.x;
  ws2[tid] = w_static[tid];
  if (tid < 128) bss[tid] = b_static[tid];
  const int ls = tid >> 1, lk = (tid & 1) * 16;
  const int ty = tid >> 4, tx = tid & 15;
  const int lbk = tid >> 3, ljb = (tid & 7) * 16;
  float acc[8][8];
#pragma unroll
  for (int r = 0; r < 8; ++r)
#pragma unroll
    for (int c = 0; c < 8; ++c) acc[r][c] = 0.f;
  __syncthreads();
  for (int kc = 0; kc < 4; ++kc) {
#pragma unroll
    for (int j4 = 0; j4 < 4; ++j4) {
      float4 v = *(const float4*)(mh_g + (size_t)b * 16384 + ls * 128 + kc * 32 + lk + 4 * j4);
      As[(lk + 4 * j4 + 0) * 132 + ls] = v.x;
      As[(lk + 4 * j4 + 1) * 132 + ls] = v.y;
      As[(lk + 4 * j4 + 2) * 132 + ls] = v.z;
      As[(lk + 4 * j4 + 3) * 132 + ls] = v.w;
    }
    {
      const float* src = Wo + (kc * 32 + lbk) * 128 + ljb;
      float* dst = Bs + lbk * 132 + ljb;
#pragma unroll
      for (int l = 0; l < 16; ++l) dst[l] = src[l];
    }
    __syncthreads();
#pragma unroll 4
    for (int kk = 0; kk < 32; ++kk) {
      float4 a0 = *(const float4*)(As + kk * 132 + ty * 8);
      float4 a1 = *(const float4*)(As + kk * 132 + ty * 8 + 4);
      float4 b0 = *(const float4*)(Bs + kk * 132 + tx * 8);
      float4 b1 = *(const float4*)(Bs + kk * 132 + tx * 8 + 4);
      float avv[8] = {a0.x, a0.y, a0.z, a0.w, a1.x, a1.y, a1.z, a1.w};
      float bvv[8] = {b0.x, b0.y, b0.z, b0.w, b1.x, b1.y, b1.z, b1.w};
#pragma unroll
      for (int r = 0; r < 8; ++r)
#pragma unroll
        for (int c = 0; c < 8; ++c) acc[r][c] = fmaf(avv[r], bvv[c], acc[r][c]);
    }
    __syncthreads();
  }
#pragma unroll
  for (int r = 0; r < 8; ++r) {
    int row = ty * 8 + r;
    float s0 = statics[b * 256 + row];
    float s1 = statics[b * 256 + 128 + row];
    float ov[8];
#pragma unroll
    for (int c = 0; c < 8; ++c) {
      int j = tx * 8 + c;
      float e0 = fmaf(s1, ws2[2 * j + 1], s0 * ws2[2 * j]) + bss[j];
      ov[c] = e0 + acc[r][c];
    }
    float4* dst = (float4*)(emb_g + (size_t)b * 16384 + row * 128 + tx * 8);
    dst[0] = make_float4(ov[0], ov[1], ov[2], ov[3]);
    dst[1] = make_float4(ov[4], ov[5], ov[6], ov[7]);
  }
}

// ---------------------------------------------------------------------------
// k_base: baseC = emb @ W1^T + wd0*dy0 + wd1*dy1, per b.
// ---------------------------------------------------------------------------
__global__ __launch_bounds__(256) void k_base(
    const float* __restrict__ emb_g, const float* __restrict__ W1,
    const float* __restrict__ W2, const float* __restrict__ w_dyn,
    const float* __restrict__ dynamics, float* __restrict__ baseC_g) {
  __shared__ __align__(16) float As[32 * 132];
  __shared__ __align__(16) float Bs[32 * 132];
  __shared__ __align__(16) float wd0[128];
  __shared__ __align__(16) float wd1[128];
  __shared__ __align__(16) float dy0[128];
  __shared__ __align__(16) float dy1[128];
  const int tid = threadIdx.x;
  const int b = (int)blockIdx.x;
  if (tid < 128) {
    float A0 = 0.f, A1 = 0.f;
    const float* w2r = W2 + tid * 128;
    for (int k = 0; k < 128; ++k) {
      float w = w2r[k];
      A0 = fmaf(w, w_dyn[2 * k], A0);
      A1 = fmaf(w, w_dyn[2 * k + 1], A1);
    }
    wd0[tid] = A0; wd1[tid] = A1;
    dy0[tid] = dynamics[b * 256 + tid];
    dy1[tid] = dynamics[b * 256 + 128 + tid];
  }
  const int ls = tid >> 1, lk = (tid & 1) * 16;
  const int ty = tid >> 4, tx = tid & 15;
  float acc[8][8];
#pragma unroll
  for (int r = 0; r < 8; ++r)
#pragma unroll
    for (int c = 0; c < 8; ++c) acc[r][c] = 0.f;
  __syncthreads();
  for (int kc = 0; kc < 4; ++kc) {
#pragma unroll
    for (int j4 = 0; j4 < 4; ++j4) {
      float4 v = *(const float4*)(emb_g + (size_t)b * 16384 + ls * 128 + kc * 32 + lk + 4 * j4);
      As[(lk + 4 * j4 + 0) * 132 + ls] = v.x;
      As[(lk + 4 * j4 + 1) * 132 + ls] = v.y;
      As[(lk + 4 * j4 + 2) * 132 + ls] = v.z;
      As[(lk + 4 * j4 + 3) * 132 + ls] = v.w;
    }
    {
      const float* src = W1 + ls * 128 + kc * 32 + lk;
#pragma unroll
      for (int l = 0; l < 16; ++l) Bs[(lk + l) * 132 + ls] = src[l];
    }
    __syncthreads();
#pragma unroll 4
    for (int kk = 0; kk < 32; ++kk) {
      float4 a0 = *(const float4*)(As + kk * 132 + ty * 8);
      float4 a1 = *(const float4*)(As + kk * 132 + ty * 8 + 4);
      float4 b0 = *(const float4*)(Bs + kk * 132 + tx * 8);
      float4 b1 = *(const float4*)(Bs + kk * 132 + tx * 8 + 4);
      float avv[8] = {a0.x, a0.y, a0.z, a0.w, a1.x, a1.y, a1.z, a1.w};
      float bvv[8] = {b0.x, b0.y, b0.z, b0.w, b1.x, b1.y, b1.z, b1.w};
#pragma unroll
      for (int r = 0; r < 8; ++r)
#pragma unroll
        for (int c = 0; c < 8; ++c) acc[r][c] = fmaf(avv[r], bvv[c], acc[r][c]);
    }
    __syncthreads();
  }
#pragma unroll
  for (int r = 0; r < 8; ++r) {
    int row = ty * 8 + r;
    float d0 = dy0[row], d1 = dy1[row];
    float ov[8];
#pragma unroll
    for (int c = 0; c < 8; ++c) {
      int h = tx * 8 + c;
      ov[c] = fmaf(wd1[h], d1, fmaf(wd0[h], d0, acc[r][c]));
    }
    float4* dst = (float4*)(baseC_g + (size_t)b * 16384 + row * 128 + tx * 8);
    dst[0] = make_float4(ov[0], ov[1], ov[2], ov[3]);
    dst[1] = make_float4(ov[4], ov[5], ov[6], ov[7]);
  }
}

// ---------------------------------------------------------------------------
// k_dec: persistent decoder, TWO batches per WG, 512 threads, grid 256.
// R21 FINAL (best measured: k_dec 1653 us, total 1992 us, no spill):
// wh[128] + w3r[32] in registers, sequential per-batch loops, rotated-hrep
// in-wave C, 4-subphase E, G-fold, 8 barriers, B-slot gumbel (LSTM on
// waves 2,3/6,7; E3's executor waves 0,1/4,5 compute their own gumbel in
// the B-slot -- hides the serial RNG chain under the LSTM).
// Closed levers (all measured): streaming W_hh (-78%, R15); fused E
// (spills: R14/R16/R18/R20); interleaved loops (spill: R14, R22);
// occupancy >2 waves/SIMD (requires dropping wh -> latency).
// ---------------------------------------------------------------------------
__global__ __launch_bounds__(512, 2) void k_dec(
    const float* __restrict__ baseC_g, const float* __restrict__ statics,
    const float* __restrict__ dynamics, const float* __restrict__ W_ih,
    const float* __restrict__ W_hh, const float* __restrict__ b_ih,
    const float* __restrict__ b_hh, const float* __restrict__ w_dec_in,
    const float* __restrict__ W2, const float* __restrict__ w_dyn,
    const float* __restrict__ W3, const float* __restrict__ v_att,
    float* __restrict__ out) {
  __shared__ __align__(16) float bC0s[32 * 512];   // [j][tid], 64 KiB
  __shared__ __align__(16) float bC1s[32 * 512];   // [j][tid], 64 KiB
  __shared__ __align__(16) float hbuf0[128], hbuf1[128];
  __shared__ __align__(16) float cbuf0[128], cbuf1[128];
  __shared__ __align__(16) float hrep0[544], hrep1[544];  // 4 copies, stride 136
  __shared__ __align__(16) float gpre0[512], gpre1[512];
  __shared__ __align__(16) float rep0[528], rep1[528];   // 4 copies, stride 132
  __shared__ __align__(16) float vrep[528];
  __shared__ __align__(16) float scb0[128], scb1[128];
  __shared__ __align__(16) float wd1c[128];
  __shared__ __align__(16) float dyn0s[128], dyn1s[128];
  __shared__ __align__(16) float sst0[256], sst1[256];
  __shared__ float rmax0[2], rmax1[2], rsum0[2], rsum1[2], rval0[2], rval1[2];
  __shared__ int ridx0[2], ridx1[2];
  __shared__ float ssel0[2], ssel1[2];
  __shared__ int ptr0S, ptr1S;

  const int tid = threadIdx.x;
  const int b0 = (int)blockIdx.x * 2;
  const int b1 = b0 + 1;

  // W_hh row -> registers (shared across both batches)
  float wh[128];
  {
    const float4* src = (const float4*)(W_hh + tid * 128);
#pragma unroll
    for (int q = 0; q < 32; ++q) {
      float4 v = src[q];
      wh[4 * q] = v.x; wh[4 * q + 1] = v.y; wh[4 * q + 2] = v.z; wh[4 * q + 3] = v.w;
    }
  }
  // Phase C layout: row u = tid>>2, k-chunk kc = tid&3. W3 slice contiguous:
  // W3[(tid>>2)*128 + (tid&3)*32 + i] == W3[tid*32 + i].
  const int uC = tid >> 2, kcC = tid & 3;
  float w3r[32];
  {
    const float4* src = (const float4*)(W3 + tid * 32);
#pragma unroll
    for (int q = 0; q < 8; ++q) {
      float4 v = src[q];
      w3r[4 * q] = v.x; w3r[4 * q + 1] = v.y; w3r[4 * q + 2] = v.z; w3r[4 * q + 3] = v.w;
    }
  }

  float a0 = 0.f, a1 = 0.f;
  {
    const float* wr = W_ih + tid * 128;
    for (int k = 0; k < 128; ++k) {
      float w = wr[k];
      a0 = fmaf(w, w_dec_in[2 * k], a0);
      a1 = fmaf(w, w_dec_in[2 * k + 1], a1);
    }
  }
  const float bsum = b_ih[tid] + b_hh[tid];

  if (tid < 128) {
    float acc1 = 0.f;
    const float* w2r = W2 + tid * 128;
    for (int k = 0; k < 128; ++k) acc1 = fmaf(w2r[k], w_dyn[2 * k + 1], acc1);
    wd1c[tid] = acc1;
    dyn0s[tid] = dynamics[b0 * 256 + 128 + tid];
    dyn1s[tid] = dynamics[b1 * 256 + 128 + tid];
    hbuf0[tid] = 0.f; cbuf0[tid] = 0.f;
    hbuf1[tid] = 0.f; cbuf1[tid] = 0.f;
    float nv = v_att[tid];
    vrep[tid] = nv; vrep[132 + tid] = nv; vrep[264 + tid] = nv; vrep[396 + tid] = nv;
  }
  if (tid < 256) {
    sst0[tid] = statics[b0 * 256 + tid];
    sst1[tid] = statics[b1 * 256 + tid];
  }
  const int sD = tid >> 2, qD = tid & 3;
  // baseC slices -> LDS (transposed: element j of thread's slice at [j][tid])
  {
    const float4* s0 = (const float4*)(baseC_g + (size_t)b0 * 16384 + sD * 128 + qD * 32);
    const float4* s1 = (const float4*)(baseC_g + (size_t)b1 * 16384 + sD * 128 + qD * 32);
#pragma unroll
    for (int j = 0; j < 8; ++j) {
      float4 v = s0[j];
      bC0s[(4 * j + 0) * 512 + tid] = v.x;
      bC0s[(4 * j + 1) * 512 + tid] = v.y;
      bC0s[(4 * j + 2) * 512 + tid] = v.z;
      bC0s[(4 * j + 3) * 512 + tid] = v.w;
      float4 w = s1[j];
      bC1s[(4 * j + 0) * 512 + tid] = w.x;
      bC1s[(4 * j + 1) * 512 + tid] = w.y;
      bC1s[(4 * j + 2) * 512 + tid] = w.z;
      bC1s[(4 * j + 3) * 512 + tid] = w.w;
    }
  }
  __syncthreads();
  float xa0 = a0 + a1, xa1 = a0 + a1;

  const int laneBase = (tid & 63) & ~3;   // lane of kc==0 thread in this group

  for (int t = 0; t < 128; ++t) {
    float gum = 0.f;   // set in the B-slot by waves 0,1 (b0) and 4,5 (b1)

    // phase A: gate pre-activation for gate-row tid, both batches
    // (sequential per-batch loops, R13-identical codegen)
    {
      float acc0 = bsum + xa0;
      const float4* hp0 = (const float4*)hbuf0;
#pragma unroll
      for (int q = 0; q < 32; ++q) {
        float4 hv = hp0[q];
        acc0 = fmaf(wh[4 * q], hv.x, acc0);
        acc0 = fmaf(wh[4 * q + 1], hv.y, acc0);
        acc0 = fmaf(wh[4 * q + 2], hv.z, acc0);
        acc0 = fmaf(wh[4 * q + 3], hv.w, acc0);
      }
      gpre0[tid] = acc0;
      float acc1v = bsum + xa1;
      const float4* hp1 = (const float4*)hbuf1;
#pragma unroll
      for (int q = 0; q < 32; ++q) {
        float4 hv = hp1[q];
        acc1v = fmaf(wh[4 * q], hv.x, acc1v);
        acc1v = fmaf(wh[4 * q + 1], hv.y, acc1v);
        acc1v = fmaf(wh[4 * q + 2], hv.z, acc1v);
        acc1v = fmaf(wh[4 * q + 3], hv.w, acc1v);
      }
      gpre1[tid] = acc1v;
    }
    __syncthreads();
    // phase B: LSTM remapped to waves 2,3 (b0) and 6,7 (b1) -- per-row math
    // identical to R17, only the executing thread changed. Idle waves
    // 0,1 (tid<128) and 4,5 (tid 256..383) -- exactly E3's executors --
    // compute their own element's gumbel here (fk threefry + element
    // threefry + logs), hiding the serial RNG chain under the LSTM.
    if (tid >= 128 && tid < 256) {
      int u = tid - 128;
      float gi = gpre0[u], gf = gpre0[128 + u], gg = gpre0[256 + u], go = gpre0[384 + u];
      float si = 1.f / (1.f + expf(-gi));
      float sf = 1.f / (1.f + expf(-gf));
      float so = 1.f / (1.f + expf(-go));
      float cn = sf * cbuf0[u] + si * tanhf(gg);
      float hn = so * tanhf(cn);
      cbuf0[u] = cn; hbuf0[u] = hn;
      hrep0[u] = hn; hrep0[136 + u] = hn;
      hrep0[272 + u] = hn; hrep0[408 + u] = hn;
    } else if (tid >= 384) {
      int u = tid - 384;
      float gi = gpre1[u], gf = gpre1[128 + u], gg = gpre1[256 + u], go = gpre1[384 + u];
      float si = 1.f / (1.f + expf(-gi));
      float sf = 1.f / (1.f + expf(-gf));
      float so = 1.f / (1.f + expf(-go));
      float cn = sf * cbuf1[u] + si * tanhf(gg);
      float hn = so * tanhf(cn);
      cbuf1[u] = cn; hbuf1[u] = hn;
      hrep1[u] = hn; hrep1[136 + u] = hn;
      hrep1[272 + u] = hn; hrep1[408 + u] = hn;
    } else {
      // tid < 128: gum for b0 element tid; 256 <= tid < 384: b1, element
      // tid-256. Same fk derivation + element mapping as R17's E3.
      const int lE = (tid < 128) ? tid : (tid - 256);
      const int bb = (tid < 128) ? b0 : b1;
      uint32_t fk0, fk1, o0, o1;
      threefry2x32(0u, 42u, 0u, (uint32_t)t, fk0, fk1);   // fold_in(key(42),t)
      threefry2x32(fk0, fk1, 0u, (uint32_t)(bb * 128 + lE), o0, o1);
      uint32_t bits = o0 ^ o1;
      float f = __uint_as_float(0x3f800000u | (bits >> 9)) - 1.0f;
      float uu = (f > 0.0f) ? f : 1.17549435e-38f;
      gum = logf(-logf(uu));
    }
    __syncthreads();
    // phase C: in-wave (h @ W3^T). Thread (uC, kcC) computes partial kcC of
    // row uC from rotated copy kcC (word base kcC*168): banks
    // {4j, 8+4j, 16+4j, 24+4j} across the 4 lanes -> conflict-free.
    // FMA chain order and 4-partial combine identical to R13's hw3p path.
    {
      const float4* hp0 = (const float4*)(hrep0 + kcC * 168);
      float p0 = 0.f;
#pragma unroll
      for (int j = 0; j < 8; ++j) {
        float4 hv = hp0[j];
        p0 = fmaf(w3r[4 * j], hv.x, p0); p0 = fmaf(w3r[4 * j + 1], hv.y, p0);
        p0 = fmaf(w3r[4 * j + 2], hv.z, p0); p0 = fmaf(w3r[4 * j + 3], hv.w, p0);
      }
      const float4* hp1 = (const float4*)(hrep1 + kcC * 168);
      float p1 = 0.f;
#pragma unroll
      for (int j = 0; j < 8; ++j) {
        float4 hv = hp1[j];
        p1 = fmaf(w3r[4 * j], hv.x, p1); p1 = fmaf(w3r[4 * j + 1], hv.y, p1);
        p1 = fmaf(w3r[4 * j + 2], hv.z, p1); p1 = fmaf(w3r[4 * j + 3], hv.w, p1);
      }
      float g0 = __shfl(p0, laneBase, 64);
      float g1 = __shfl(p0, laneBase + 1, 64);
      float g2 = __shfl(p0, laneBase + 2, 64);
      float g3 = __shfl(p0, laneBase + 3, 64);
      rep0[kcC * 132 + uC] = ((g0 + g1) + g2) + g3;
      float h0v = __shfl(p1, laneBase, 64);
      float h1v = __shfl(p1, laneBase + 1, 64);
      float h2v = __shfl(p1, laneBase + 2, 64);
      float h3v = __shfl(p1, laneBase + 3, 64);
      rep1[kcC * 132 + uC] = ((h0v + h1v) + h2v) + h3v;
    }
    __syncthreads();
    // phase D: score partials, both batches (sequential per-batch loops,
    // R13-identical; bC reads conflict-free: bank = tid%32)
    {
      const float* vp = vrep + 164 * qD;
      const float* h0 = rep0 + 164 * qD;
      float acc = 0.f;
#pragma unroll
      for (int j = 0; j < 32; ++j)
        acc = fmaf(vp[j], tanhf(bC0s[j * 512 + tid] + h0[j]), acc);
      acc += __shfl_xor(acc, 1, 64);
      acc += __shfl_xor(acc, 2, 64);
      if (qD == 0) scb0[sD] = acc;
      const float* h1 = rep1 + 164 * qD;
      float acc1v = 0.f;
#pragma unroll
      for (int j = 0; j < 32; ++j)
        acc1v = fmaf(vp[j], tanhf(bC1s[j * 512 + tid] + h1[j]), acc1v);
      acc1v += __shfl_xor(acc1v, 1, 64);
      acc1v += __shfl_xor(acc1v, 2, 64);
      if (qD == 0) scb1[sD] = acc1v;
    }
    __syncthreads();
    // phase E: log-softmax + gumbel argmax; group0 = tid<128 (b0),
    // group1 = 256<=tid<384 (b1); R17's exact 2-wave shfl+LDS structure,
    // with the gumbel already in-register from the B-slot.
    const int g0 = (tid < 128);
    const int g1 = (tid >= 256 && tid < 384);
    const int lE = g0 ? tid : (tid - 256);
    float scv = 0.f, lpv = 0.f, mrow = 0.f;
    if (g0 || g1) {
      scv = g0 ? scb0[lE] : scb1[lE];
      float m = scv;
#pragma unroll
      for (int off = 32; off; off >>= 1) m = fmaxf(m, __shfl_xor(m, off, 64));
      if ((lE & 63) == 0) { if (g0) rmax0[lE >> 6] = m; else rmax1[lE >> 6] = m; }
    }
    __syncthreads();
    if (g0 || g1) {
      mrow = g0 ? fmaxf(rmax0[0], rmax0[1]) : fmaxf(rmax1[0], rmax1[1]);
      float sum = expf(scv - mrow);
#pragma unroll
      for (int off = 32; off; off >>= 1) sum += __shfl_xor(sum, off, 64);
      if ((lE & 63) == 0) { if (g0) rsum0[lE >> 6] = sum; else rsum1[lE >> 6] = sum; }
    }
    __syncthreads();
    if (g0 || g1) {
      float sum = g0 ? (rsum0[0] + rsum0[1]) : (rsum1[0] + rsum1[1]);
      lpv = (scv - mrow) - logf(sum);
      float val = lpv - gum;
      int idx = lE;
#pragma unroll
      for (int off = 32; off; off >>= 1) {
        float ov = __shfl_xor(val, off, 64);
        int oi = __shfl_xor(idx, off, 64);
        if (ov > val || (ov == val && oi < idx)) { val = ov; idx = oi; }
      }
      if ((lE & 63) == 0) {
        if (g0) { rval0[lE >> 6] = val; ridx0[lE >> 6] = idx; }
        else    { rval1[lE >> 6] = val; ridx1[lE >> 6] = idx; }
      }
    }
    __syncthreads();
    if (g0 || g1) {
      int p;
      if (g0) { float v0 = rval0[0], v1 = rval0[1];
                p = (v1 > v0) ? ridx0[1] : ridx0[0]; }
      else    { float v0 = rval1[0], v1 = rval1[1];
                p = (v1 > v0) ? ridx1[1] : ridx1[0]; }
      p &= 127;
      int bb = g0 ? b0 : b1;
      if (lE == 0) {
        if (g0) ptr0S = p; else ptr1S = p;
        out[bb * 128 + t] = (float)p;
      }
      if (lE == p) {
        out[65536 + bb * 128 + t] = lpv;
        const float* sst = g0 ? sst0 : sst1;
        float s0v = sst[p], s1v = sst[128 + p];
        if (g0) { ssel0[0] = s0v; ssel0[1] = s1v; }
        else    { ssel1[0] = s0v; ssel1[1] = s1v; }
      }
    }
    __syncthreads();
    // phase G: rank-1 baseC corrections (own-column LDS, single-owner, no
    // cross-thread hazard) + dyn zeroing folded into the reading wave +
    // next decoder inputs. No trailing barrier.
    {
      int p0 = ptr0S, p1 = ptr1S;
      if (sD == p0) {
        float d1 = dyn0s[p0];
#pragma unroll
        for (int i = 0; i < 32; ++i)
          bC0s[i * 512 + tid] = fmaf(-wd1c[qD * 32 + i], d1, bC0s[i * 512 + tid]);
        if (qD == 0) dyn0s[p0] = 0.f;
      }
      if (sD == p1) {
        float d1 = dyn1s[p1];
#pragma unroll
        for (int i = 0; i < 32; ++i)
          bC1s[i * 512 + tid] = fmaf(-wd1c[qD * 32 + i], d1, bC1s[i * 512 + tid]);
        if (qD == 0) dyn1s[p1] = 0.f;
      }
      xa0 = fmaf(a0, ssel0[0], a1 * ssel0[1]);
      xa1 = fmaf(a0, ssel1[0], a1 * ssel1[1]);
    }
  }
}

// ---------------------------------------------------------------------------
extern "C" __attribute__((visibility("default")))
void kernel_launch(void* const* d_in, const int* in_sizes, int n_in,
                   void* d_out, int out_size, void* d_ws, size_t ws_size,
                   hipStream_t stream) {
  (void)hipGetLastError();
  (void)in_sizes; (void)n_in; (void)out_size; (void)ws_size;

  const float* statics  = (const float*)d_in[0];
  const float* dynamics = (const float*)d_in[1];
  // d_in[2] = distances: unused by the reference; never touched.
  const float* w_static = (const float*)d_in[3];
  const float* b_static = (const float*)d_in[4];
  const float* Wq  = (const float*)d_in[5];
  const float* Wk  = (const float*)d_in[6];
  const float* Wv  = (const float*)d_in[7];
  const float* Wo  = (const float*)d_in[8];
  const float* w_dyn    = (const float*)d_in[9];
  const float* w_dec_in = (const float*)d_in[10];
  const float* W_ih = (const float*)d_in[11];
  const float* W_hh = (const float*)d_in[12];
  const float* b_ih = (const float*)d_in[13];
  const float* b_hh = (const float*)d_in[14];
  const float* W1   = (const float*)d_in[15];
  const float* W2   = (const float*)d_in[16];
  const float* W3   = (const float*)d_in[17];
  const float* v_att = (const float*)d_in[18];
  float* wsA = (float*)d_ws;            // emb
  float* wsB = wsA + 8388608;           // mh, then baseC
  float* outp = (float*)d_out;

  k_att<<<dim3(4096), dim3(256), 0, stream>>>(
      statics, w_static, b_static, Wq, Wk, Wv, wsB);
  k_out<<<dim3(512), dim3(256), 0, stream>>>(
      wsB, Wo, statics, w_static, b_static, wsA);
  k_base<<<dim3(512), dim3(256), 0, stream>>>(
      wsA, W1, W2, w_dyn, dynamics, wsB);
  k_dec<<<dim3(256), dim3(512), 0, stream>>>(
      wsB, statics, dynamics, W_ih, W_hh, b_ih, b_hh, w_dec_in,
      W2, w_dyn, W3, v_att, outp);
}